// Round 17
// baseline (153.566 us; speedup 1.0000x reference)
//
#include <hip/hip_runtime.h>
#include <stdint.h>

// ============================================================================
// Fused attention block: out = proj( MHA_causal( x @ w_attn + b_attn ) )
// B=4, S=2048, E=1024, H=16, D=64.  bf16 MFMA path, f32 accumulation.
//
// Pipeline:
//   1) cast_x_kernel:        x f32 -> xb bf16                  [8192][1024]
//   2) transpose_cast:       w_attn -> wat bf16 [3072][1024] (B^T form)
//                            w_proj -> wpt bf16 [1024][1024]
//   3) gemm128<bf16,FUSE_VT>: qkv(Q,K) + vt(V) = xb @ wat^T + b [8192][3072]
//        v5: BM=BN=128, BK=32, 256 thr / 4 waves (2x2 of 64x64) -- same
//        per-wave MFMA:ds_read intensity as the 256x128 version, but LDS =
//        48KB triple-buffer -> 3 blocks/CU and grid 1536 = exactly 2 full
//        dispatch rounds (768 resident). Counted vmcnt(4), 1 barrier/K-tile,
//        slot^=(row>>1)&3 swizzle, XCD-bijective swizzle.
//        V-blocks (n0>=2048): coalesced vt epilogue through LDS overlay
//        (key-permute at LDS write; 16B stores, contiguous 256B runs).
//        Q columns (<1024) pre-scaled by log2e/8 for exp2-domain softmax.
//   4) flash_kernel v6+XCD:  ob = causal attention             [8192][1024]
//        512 thr, 8 waves x 16 rows, paired (bx,15-bx) -> 36 steps/block,
//        K/V dbuf, no-max exp2 softmax, in-lane P pack, XCD-affinity remap.
//   5) gemm128<float>:       out = ob @ wpt^T + b_proj         [8192][1024]
//        grid 512 -> 2-3 blocks/CU (was 256 = 1/CU, zero co-residency).
// ============================================================================

typedef __bf16 bf16;
typedef __bf16 bf16x4 __attribute__((ext_vector_type(4)));
typedef __bf16 bf16x8 __attribute__((ext_vector_type(8)));
typedef float  f32x4  __attribute__((ext_vector_type(4)));

#define DEV __device__ __forceinline__

// async global->LDS, 16B per lane. LDS dest: wave-uniform base; HW adds lane*16.
DEV void async_copy16(bf16* lds, const bf16* g) {
  __builtin_amdgcn_global_load_lds(
      (__attribute__((address_space(1))) void*)(uintptr_t)g,
      (__attribute__((address_space(3))) void*)(uint32_t)(uintptr_t)lds,
      16, 0, 0);
}

// ---------------------------------------------------------------------------
// prep kernels
// ---------------------------------------------------------------------------
__global__ __launch_bounds__(256) void cast_x_kernel(const float* __restrict__ in,
                                                     bf16* __restrict__ out, int n4) {
  int i = blockIdx.x * blockDim.x + threadIdx.x;
  int stride = gridDim.x * blockDim.x;
  for (; i < n4; i += stride) {
    float4 v = ((const float4*)in)[i];
    bf16x4 o = { (bf16)v.x, (bf16)v.y, (bf16)v.z, (bf16)v.w };
    *(bf16x4*)(out + (size_t)i * 4) = o;
  }
}

// W [Kd][Nd] f32 row-major  ->  Wt [Nd][Kd] bf16 row-major
__global__ __launch_bounds__(256) void transpose_cast_kernel(const float* __restrict__ W,
                                                             bf16* __restrict__ Wt,
                                                             int Kd, int Nd) {
  __shared__ alignas(16) bf16 T[64 * 80];   // 64x64 tile, padded rows
  const int t = threadIdx.x;
  const int n0 = blockIdx.x * 64;
  const int k0 = blockIdx.y * 64;
#pragma unroll
  for (int i = 0; i < 4; ++i) {
    int idx = t + i * 256;            // 1024 float4s
    int r  = idx >> 4;                // k row in tile
    int c4 = (idx & 15) * 4;          // n col in tile
    float4 v = *(const float4*)(W + (size_t)(k0 + r) * Nd + n0 + c4);
    bf16x4 o = { (bf16)v.x, (bf16)v.y, (bf16)v.z, (bf16)v.w };
    *(bf16x4*)(&T[r * 80 + c4]) = o;
  }
  __syncthreads();
#pragma unroll
  for (int i = 0; i < 2; ++i) {
    int idx = t + i * 256;            // 512 out-chunks
    int n = idx >> 3;
    int c = idx & 7;
    bf16x8 o;
#pragma unroll
    for (int j = 0; j < 8; ++j) o[j] = T[(c * 8 + j) * 80 + n];
    *(bf16x8*)(Wt + (size_t)(n0 + n) * Kd + k0 + c * 8) = o;
  }
}

// ---------------------------------------------------------------------------
// GEMM v7 (gemm128): C[M][N] = A[M][K] @ Bt[N][K]^T + bias[N]
// BM=BN=128, BK=32. 256 thr = 4 waves (2M x 2N), 64x64 per wave.
// TRIPLE-buffered LDS (48 KB -> 3 blocks/CU). ONE barrier per K-tile:
//   [vmcnt(4); s_barrier; stage(kt+2) 4 loads; ds_read 8; setprio MFMA x16]
// LDS slot swizzle: slot ^= (row>>1)&3 (involution, source-preswizzled).
// FUSE_VT + n0>=2048: coalesced vt epilogue through LDS overlay.
// Requires: M%128==0, N%128==0, K%32==0, K/32>=2, grid%8==0.
// ---------------------------------------------------------------------------
template <typename OutT, bool FUSE_VT>
__global__ __launch_bounds__(256, 4) void gemm128_kernel(const bf16* __restrict__ A,
                                                         const bf16* __restrict__ Bt,
                                                         const float* __restrict__ bias,
                                                         OutT* __restrict__ C,
                                                         bf16* __restrict__ vtout,
                                                         int M, int N, int K,
                                                         float qscale, int qcols,
                                                         int nbx) {
  __shared__ alignas(16) char smem[49152];               // 48 KB
  auto As = (bf16(*)[128 * 32])smem;                     // As[3][4096] (24 KB)
  auto Bs = (bf16(*)[128 * 32])(smem + 24576);           // Bs[3][4096] (24 KB)

  const int tid  = threadIdx.x;
  const int lane = tid & 63;
  const int w    = tid >> 6;          // 0..3
  const int wm = w >> 1, wn = w & 1;
  const int l15 = lane & 15, l16 = lane >> 4;

  const int nwg = (int)gridDim.x;
  const int cpx = nwg >> 3;
  const int swz = ((int)blockIdx.x & 7) * cpx + ((int)blockIdx.x >> 3);
  const int m0 = (swz / nbx) * 128;
  const int n0 = (swz % nbx) * 128;

  // staging: tile = 128 rows x 32 cols = 512 chunks(16B); thread covers
  // chunks tid and 256+tid. chunk c -> row c>>2, slot c&3 (swizzled).
  const int r0_ = tid >> 2, s0c = tid & 3;
  const int r1_ = r0_ + 64;
  const bf16* srcA0 = A  + (size_t)(m0 + r0_) * K + 8 * (s0c ^ ((r0_ >> 1) & 3));
  const bf16* srcA1 = A  + (size_t)(m0 + r1_) * K + 8 * (s0c ^ ((r1_ >> 1) & 3));
  const bf16* srcB0 = Bt + (size_t)(n0 + r0_) * K + 8 * (s0c ^ ((r0_ >> 1) & 3));
  const bf16* srcB1 = Bt + (size_t)(n0 + r1_) * K + 8 * (s0c ^ ((r1_ >> 1) & 3));

#define STAGE_TILE(buf, kt)                                         \
  {                                                                 \
    const int k0_ = (kt) * 32;                                      \
    async_copy16(&As[buf][(w * 64) * 8],         srcA0 + k0_);      \
    async_copy16(&As[buf][(256 + w * 64) * 8],   srcA1 + k0_);      \
    async_copy16(&Bs[buf][(w * 64) * 8],         srcB0 + k0_);      \
    async_copy16(&Bs[buf][(256 + w * 64) * 8],   srcB1 + k0_);      \
  }

  f32x4 acc[4][4];
  f32x4 zf = {0.f, 0.f, 0.f, 0.f};
#pragma unroll
  for (int i = 0; i < 4; ++i)
#pragma unroll
    for (int j = 0; j < 4; ++j) acc[i][j] = zf;

  const int KT = K >> 5;
  STAGE_TILE(0, 0)
  STAGE_TILE(1, 1)

  const int soff = 8 * (l16 ^ ((l15 >> 1) & 3));

  int bufc = 0;
  int bufs = 2;
  for (int kt = 0; kt < KT; ++kt) {
    if (kt < KT - 1) { asm volatile("s_waitcnt vmcnt(4)" ::: "memory"); }
    else             { asm volatile("s_waitcnt vmcnt(0)" ::: "memory"); }
    __builtin_amdgcn_s_barrier();
    asm volatile("" ::: "memory");
    if (kt + 2 < KT) STAGE_TILE(bufs, kt + 2)

    bf16x8 bfr[4], afr[4];
#pragma unroll
    for (int n = 0; n < 4; ++n) {
      int rb = wn * 64 + n * 16 + l15;
      bfr[n] = *(const bf16x8*)(&Bs[bufc][rb * 32 + soff]);
    }
#pragma unroll
    for (int m = 0; m < 4; ++m) {
      int ra = wm * 64 + m * 16 + l15;
      afr[m] = *(const bf16x8*)(&As[bufc][ra * 32 + soff]);
    }
    __builtin_amdgcn_s_setprio(1);
#pragma unroll
    for (int m = 0; m < 4; ++m)
#pragma unroll
      for (int n = 0; n < 4; ++n)
        acc[m][n] = __builtin_amdgcn_mfma_f32_16x16x32_bf16(afr[m], bfr[n], acc[m][n], 0, 0, 0);
    __builtin_amdgcn_s_setprio(0);
    asm volatile("" ::: "memory");
    bufc = (bufc == 2) ? 0 : bufc + 1;
    bufs = (bufs == 2) ? 0 : bufs + 1;
  }

  // ---- epilogue
  if (FUSE_VT && n0 >= 2048) {
    // V-block: coalesced vt writes via LDS overlay T[128 cols][136 rows-pad].
    // Key permute applied at LDS write (pos(key0+j) = pos(key0)|j for j<4).
    __syncthreads();                         // all K-loop LDS reads complete
    bf16* T = (bf16*)smem;                   // 128*136*2 = 34.8 KB <= 48 KB
#pragma unroll
    for (int n = 0; n < 4; ++n) {
      int c = wn * 64 + n * 16 + l15;        // 0..127 (output col within tile)
      float bb = bias[n0 + c];
#pragma unroll
      for (int m = 0; m < 4; ++m) {
        int r0q = wm * 64 + m * 16 + l16 * 4;   // quad base row; key0 % 4 == 0
        int key0 = r0q & 63;
        int pos0 = (key0 & 32) | (((key0 >> 2) & 3) << 3) | (((key0 >> 4) & 1) << 2);
        int rp = (r0q & ~63) | pos0;
        bf16x4 q = { (bf16)(acc[m][n][0] + bb), (bf16)(acc[m][n][1] + bb),
                     (bf16)(acc[m][n][2] + bb), (bf16)(acc[m][n][3] + bb) };
        *(bf16x4*)(&T[c * 136 + rp]) = q;
      }
    }
    __syncthreads();
    const int b_  = m0 >> 11;                // batch (tiles never straddle)
    const int s0_ = m0 & 2047;
    const int ck  = tid & 15;                // 16B chunk within a 256B run
#pragma unroll
    for (int pass = 0; pass < 8; ++pass) {
      int c = pass * 16 + (tid >> 4);        // 0..127
      int colg = n0 + c - 2048;
      int hh = colg >> 6, d = colg & 63;
      bf16x8 v = *(const bf16x8*)(&T[c * 136 + ck * 8]);
      *(bf16x8*)(vtout + ((size_t)(b_ * 16 + hh) * 64 + d) * 2048 + s0_ + ck * 8) = v;
    }
    return;
  }
  // Q/K (and proj) columns: direct C writes
#pragma unroll
  for (int n = 0; n < 4; ++n) {
    int col = n0 + wn * 64 + n * 16 + l15;
    float bb = bias[col];
    float sc2 = (col < qcols) ? qscale : 1.0f;
#pragma unroll
    for (int m = 0; m < 4; ++m) {
#pragma unroll
      for (int reg = 0; reg < 4; ++reg) {
        int row = m0 + wm * 64 + m * 16 + l16 * 4 + reg;
        C[(size_t)row * N + col] = (OutT)((acc[m][n][reg] + bb) * sc2);
      }
    }
  }
#undef STAGE_TILE
}

// ---------------------------------------------------------------------------
// Flash attention v6 + XCD-affinity remap. Q-tile 128 rows, 8 waves x 16.
// 1D grid 512: bh = ((i>>6)<<3)|(i&7), bx = (i>>3)&7 -- all 8 blocks sharing
// a bh have the same i%8 residue -> same XCD -> K/V L2 reuse.
// Pair (bx, 15-bx) processed sequentially -> 36 KV-steps/block.
// NO-MAX exp2 softmax (Q pre-scaled by log2e/8; masked entries exp2(-1e30)=0).
// P never touches LDS (vt key axis pre-permuted at QKV-GEMM epilogue;
// in-lane pack: pb[kc] = {sv[2kc][0..3], sv[2kc+1][0..3]}).
// S^T = mfma(K,Q): lane holds col q = lane&15, 16 keys = kf*16 + l16*4 + reg.
// O^T = mfma(V^T,P^T): lane holds col q = lane&15, d = nf*16 + l16*4 + reg.
// LDS = 32 KB (K/V double-buffer only).
// ---------------------------------------------------------------------------
__global__ __launch_bounds__(512, 4) void flash_kernel(const bf16* __restrict__ qkv,
                                                       const bf16* __restrict__ vt,
                                                       bf16* __restrict__ obuf) {
  constexpr int S = 2048, E3 = 3072;
  __shared__ alignas(16) bf16 Ks[2][64 * 64];
  __shared__ alignas(16) bf16 Vs[2][64 * 64];   // V^T tile (key-permuted cols)

  const int tid  = threadIdx.x;
  const int lane = tid & 63;
  const int w    = tid >> 6;
  const int i   = (int)blockIdx.x;            // 0..511
  const int bh  = ((i >> 6) << 3) | (i & 7);  // same-bh blocks share i%8 (XCD)
  const int bx  = (i >> 3) & 7;               // 0..7 -> tiles bx and 15-bx
  const int b = bh >> 4, h = bh & 15;
  const int l15 = lane & 15, l16 = lane >> 4;

  // staging geometry (wave w stages 1KB chunk w of each 64x64 tile)
  const int sr  = w * 8 + (lane >> 3);   // row 0..63 within tile
  const int scc = lane & 7;              // 16B slot
  const bf16* kstage = qkv + (size_t)(b * S + sr) * E3 + 1024 + h * 64 + 8 * (scc ^ (sr & 7));
  const bf16* vstage = vt + (size_t)(bh * 64 + sr) * S + 8 * (scc ^ (sr & 7));

  // hoisted LDS byte offsets (row stride 128B; XOR term reduces to l15&7)
  const int xsw = l15 & 7;
  const uint32_t rdA = (uint32_t)(l15 * 128 + 16 * (l16 ^ xsw));        // chunk 0
  const uint32_t rdB = (uint32_t)(l15 * 128 + 16 * ((4 + l16) ^ xsw));  // chunk 1

#define KV_STAGE(buf, kv0_)                                        \
  {                                                                \
    async_copy16(Ks[buf] + w * 512, kstage + (size_t)(kv0_) * E3); \
    async_copy16(Vs[buf] + w * 512, vstage + (kv0_));              \
  }

  for (int half = 0; half < 2; ++half) {
    const int t = half ? (15 - bx) : bx;
    const int q0 = t * 128;
    const int wq0 = q0 + w * 16;         // first q row owned by this wave
    const int nsteps = 2 * t + 2;        // even

    KV_STAGE(0, 0)

    // Q fragments global->reg (B-operand: col q = l15, k-chunk dk*32+l16*8)
    bf16x8 qf[2];
    {
      const bf16* qbase = qkv + (size_t)(b * S + wq0 + l15) * E3 + h * 64;
#pragma unroll
      for (int dk = 0; dk < 2; ++dk)
        qf[dk] = *(const bf16x8*)(qbase + (dk * 4 + l16) * 8);
    }

    float lstate = 0.f;
    f32x4 oacc[4];
    f32x4 zf = {0.f, 0.f, 0.f, 0.f};
#pragma unroll
    for (int i2 = 0; i2 < 4; ++i2) oacc[i2] = zf;

    __syncthreads();   // step-0 K/V staged (vmcnt drained by barrier)

#define FLASH_STEP(CUR, STEPIDX)                                                  \
    {                                                                             \
      const int kv0 = (STEPIDX) * 64;                                             \
      if ((STEPIDX) + 1 < nsteps) KV_STAGE((CUR) ^ 1, kv0 + 64)                   \
      if (kv0 <= wq0 + 15) {   /* wave-uniform dead-step skip */                  \
        f32x4 sv[4];                                                              \
        _Pragma("unroll")                                                         \
        for (int kf = 0; kf < 4; ++kf) sv[kf] = zf;                               \
        __builtin_amdgcn_s_setprio(1);                                            \
        _Pragma("unroll")                                                         \
        for (int kf = 0; kf < 4; ++kf) {                                          \
          bf16x8 k0 = *(const bf16x8*)((const char*)Ks[CUR] + rdA + kf * 2048);   \
          sv[kf] = __builtin_amdgcn_mfma_f32_16x16x32_bf16(k0, qf[0], sv[kf], 0, 0, 0); \
          bf16x8 k1 = *(const bf16x8*)((const char*)Ks[CUR] + rdB + kf * 2048);   \
          sv[kf] = __builtin_amdgcn_mfma_f32_16x16x32_bf16(k1, qf[1], sv[kf], 0, 0, 0); \
        }                                                                         \
        __builtin_amdgcn_s_setprio(0);                                            \
        if (kv0 + 63 > wq0) {   /* causal mask (diagonal-crossing steps only) */  \
          const int qrow_ = wq0 + l15;                                            \
          _Pragma("unroll")                                                       \
          for (int kf = 0; kf < 4; ++kf)                                          \
            _Pragma("unroll")                                                     \
            for (int reg = 0; reg < 4; ++reg) {                                   \
              int key = kv0 + kf * 16 + l16 * 4 + reg;                            \
              if (key > qrow_) sv[kf][reg] = -1e30f;                              \
            }                                                                     \
        }                                                                         \
        float rsum = 0.f;                                                         \
        _Pragma("unroll")                                                         \
        for (int kf = 0; kf < 4; ++kf)                                            \
          _Pragma("unroll")                                                       \
          for (int reg = 0; reg < 4; ++reg) {                                     \
            float p = __builtin_amdgcn_exp2f(sv[kf][reg]);                        \
            sv[kf][reg] = p;                                                      \
            rsum += p;                                                            \
          }                                                                       \
        rsum += __shfl_xor(rsum, 16);                                             \
        rsum += __shfl_xor(rsum, 32);                                             \
        lstate += rsum;                                                           \
        /* in-lane P pack: pb[kc] covers permuted key positions kc*32+8g+j */     \
        bf16x8 pb[2];                                                             \
        _Pragma("unroll")                                                         \
        for (int kc = 0; kc < 2; ++kc) {                                          \
          bf16x8 tq;                                                              \
          tq[0] = (bf16)sv[2 * kc][0];  tq[1] = (bf16)sv[2 * kc][1];              \
          tq[2] = (bf16)sv[2 * kc][2];  tq[3] = (bf16)sv[2 * kc][3];              \
          tq[4] = (bf16)sv[2 * kc + 1][0]; tq[5] = (bf16)sv[2 * kc + 1][1];       \
          tq[6] = (bf16)sv[2 * kc + 1][2]; tq[7] = (bf16)sv[2 * kc + 1][3];       \
          pb[kc] = tq;                                                            \
        }                                                                         \
        __builtin_amdgcn_s_setprio(1);                                            \
        _Pragma("unroll")                                                         \
        for (int nf = 0; nf < 4; ++nf) {                                          \
          bf16x8 vf0 = *(const bf16x8*)((const char*)Vs[CUR] + rdA + nf * 2048);  \
          oacc[nf] = __builtin_amdgcn_mfma_f32_16x16x32_bf16(vf0, pb[0], oacc[nf], 0, 0, 0); \
          bf16x8 vf1 = *(const bf16x8*)((const char*)Vs[CUR] + rdB + nf * 2048);  \
          oacc[nf] = __builtin_amdgcn_mfma_f32_16x16x32_bf16(vf1, pb[1], oacc[nf], 0, 0, 0); \
        }                                                                         \
        __builtin_amdgcn_s_setprio(0);                                            \
      }                                                                           \
      __syncthreads();   /* next buffer staged + all waves done with CUR */       \
    }

    for (int step = 0; step < nsteps; step += 2) {
      FLASH_STEP(0, step)
      FLASH_STEP(1, step + 1)
    }
#undef FLASH_STEP

    // ---- normalize and store: lane owns q row; d = nf*16 + l16*4 + reg
    float inv = 1.0f / lstate;
    int qrow = wq0 + l15;
#pragma unroll
    for (int nf = 0; nf < 4; ++nf) {
      bf16x4 o4 = { (bf16)(oacc[nf][0] * inv), (bf16)(oacc[nf][1] * inv),
                    (bf16)(oacc[nf][2] * inv), (bf16)(oacc[nf][3] * inv) };
      *(bf16x4*)(obuf + (size_t)(b * S + qrow) * 1024 + h * 64 + nf * 16 + l16 * 4) = o4;
    }
  }
#undef KV_STAGE
}

// ---------------------------------------------------------------------------
extern "C" void kernel_launch(void* const* d_in, const int* in_sizes, int n_in,
                              void* d_out, int out_size, void* d_ws, size_t ws_size,
                              hipStream_t stream) {
  (void)in_sizes; (void)n_in; (void)out_size; (void)ws_size;
  const float* x      = (const float*)d_in[0];
  const float* w_attn = (const float*)d_in[1];
  const float* b_attn = (const float*)d_in[2];
  const float* w_proj = (const float*)d_in[3];
  const float* b_proj = (const float*)d_in[4];
  float* out = (float*)d_out;

  char* ws = (char*)d_ws;
  bf16* xb  = (bf16*)(ws + 0);          // 8192*1024*2  = 16777216
  bf16* wat = (bf16*)(ws + 16777216);   // 3072*1024*2  =  6291456
  bf16* wpt = (bf16*)(ws + 23068672);   // 1024*1024*2  =  2097152
  bf16* qkv = (bf16*)(ws + 25165824);   // 8192*3072*2  = 50331648
  bf16* vt  = (bf16*)(ws + 75497472);   // 64*64*2048*2 = 16777216
  bf16* ob  = (bf16*)(ws + 92274688);   // 8192*1024*2  = 16777216 (end 109051904)

  const float QSCALE = 0.18033688011112042f;   // log2(e) / sqrt(64)

  cast_x_kernel<<<2048, 256, 0, stream>>>(x, xb, 8192 * 1024 / 4);
  transpose_cast_kernel<<<dim3(48, 16), 256, 0, stream>>>(w_attn, wat, 1024, 3072);
  transpose_cast_kernel<<<dim3(16, 16), 256, 0, stream>>>(w_proj, wpt, 1024, 1024);
  // QKV (+fused V-transpose): grid (8192/128)*(3072/128) = 64*24 = 1536 (%8==0)
  gemm128_kernel<bf16, true><<<1536, 256, 0, stream>>>(xb, wat, b_attn, qkv, vt,
                                                       8192, 3072, 1024, QSCALE, 1024, 24);
  flash_kernel<<<512, 512, 0, stream>>>(qkv, vt, ob);
  // proj: grid (8192/128)*(1024/128) = 64*8 = 512 (%8==0)
  gemm128_kernel<float, false><<<512, 256, 0, stream>>>(ob, wpt, b_proj, out, nullptr,
                                                        8192, 1024, 1024, 1.0f, 0, 8);
}

// Round 18
// 146.339 us; speedup vs baseline: 1.0494x; 1.0494x over previous
//
#include <hip/hip_runtime.h>
#include <stdint.h>

// ============================================================================
// Fused attention block: out = proj( MHA_causal( x @ w_attn + b_attn ) )
// B=4, S=2048, E=1024, H=16, D=64.  bf16 MFMA path, f32 accumulation.
//
// Pipeline:
//   1) cast_x_kernel:        x f32 -> xb bf16                  [8192][1024]
//   2) transpose_cast:       w_attn -> wat bf16 [3072][1024] (B^T form)
//                            w_proj -> wpt bf16 [1024][1024]
//   3) gemm256<bf16,FUSE_VT>: qkv(Q,K) + vt(V) = xb @ wat^T + b [8192][3072]
//        BK=32, triple-buffer (72KB, 2 blocks/CU), counted vmcnt(3),
//        1 barrier/K-tile, slot swizzle, XCD swizzle. V-blocks: coalesced
//        vt epilogue via LDS overlay (key-permute at LDS write).
//        (Round-17's 128^2 tile regressed: FETCH +15%, occupancy flat.)
//        Q columns (<1024) pre-scaled by log2e/8 for exp2-domain softmax.
//   4) flash_kernel v6+XCD:  ob = causal attention             [8192][1024]
//        512 thr, 8 waves x 16 rows, paired (bx,15-bx) -> 36 steps/block,
//        K/V dbuf, no-max exp2 softmax, in-lane P pack, XCD-affinity remap.
//   5) gemm128<float>:       out = ob @ wpt^T + b_proj         [8192][1024]
//        128^2 tile, 512 blocks -> 2x co-residency of the 256-block version;
//        proj's B (2MB) is L2-resident so the small-tile FETCH penalty is
//        absorbed by L2.
// ============================================================================

typedef __bf16 bf16;
typedef __bf16 bf16x4 __attribute__((ext_vector_type(4)));
typedef __bf16 bf16x8 __attribute__((ext_vector_type(8)));
typedef float  f32x4  __attribute__((ext_vector_type(4)));

#define DEV __device__ __forceinline__

// async global->LDS, 16B per lane. LDS dest: wave-uniform base; HW adds lane*16.
DEV void async_copy16(bf16* lds, const bf16* g) {
  __builtin_amdgcn_global_load_lds(
      (__attribute__((address_space(1))) void*)(uintptr_t)g,
      (__attribute__((address_space(3))) void*)(uint32_t)(uintptr_t)lds,
      16, 0, 0);
}

// ---------------------------------------------------------------------------
// prep kernels
// ---------------------------------------------------------------------------
__global__ __launch_bounds__(256) void cast_x_kernel(const float* __restrict__ in,
                                                     bf16* __restrict__ out, int n4) {
  int i = blockIdx.x * blockDim.x + threadIdx.x;
  int stride = gridDim.x * blockDim.x;
  for (; i < n4; i += stride) {
    float4 v = ((const float4*)in)[i];
    bf16x4 o = { (bf16)v.x, (bf16)v.y, (bf16)v.z, (bf16)v.w };
    *(bf16x4*)(out + (size_t)i * 4) = o;
  }
}

// W [Kd][Nd] f32 row-major  ->  Wt [Nd][Kd] bf16 row-major
__global__ __launch_bounds__(256) void transpose_cast_kernel(const float* __restrict__ W,
                                                             bf16* __restrict__ Wt,
                                                             int Kd, int Nd) {
  __shared__ alignas(16) bf16 T[64 * 80];   // 64x64 tile, padded rows
  const int t = threadIdx.x;
  const int n0 = blockIdx.x * 64;
  const int k0 = blockIdx.y * 64;
#pragma unroll
  for (int i = 0; i < 4; ++i) {
    int idx = t + i * 256;            // 1024 float4s
    int r  = idx >> 4;                // k row in tile
    int c4 = (idx & 15) * 4;          // n col in tile
    float4 v = *(const float4*)(W + (size_t)(k0 + r) * Nd + n0 + c4);
    bf16x4 o = { (bf16)v.x, (bf16)v.y, (bf16)v.z, (bf16)v.w };
    *(bf16x4*)(&T[r * 80 + c4]) = o;
  }
  __syncthreads();
#pragma unroll
  for (int i = 0; i < 2; ++i) {
    int idx = t + i * 256;            // 512 out-chunks
    int n = idx >> 3;
    int c = idx & 7;
    bf16x8 o;
#pragma unroll
    for (int j = 0; j < 8; ++j) o[j] = T[(c * 8 + j) * 80 + n];
    *(bf16x8*)(Wt + (size_t)(n0 + n) * Kd + k0 + c * 8) = o;
  }
}

// ---------------------------------------------------------------------------
// GEMM v6 (gemm256): C[M][N] = A[M][K] @ Bt[N][K]^T + bias[N]
// BM=256, BN=128, BK=32. 512 thr = 8 waves (4M x 2N), 64x64 per wave.
// Triple-buffered LDS (72 KB, 2 blocks/CU), one barrier/K-tile, counted
// vmcnt(3), slot^=(row>>1)&3 swizzle, XCD-bijective block swizzle.
// FUSE_VT + n0>=2048: coalesced vt epilogue through LDS overlay.
// ---------------------------------------------------------------------------
template <typename OutT, bool FUSE_VT>
__global__ __launch_bounds__(512, 4) void gemm256_kernel(const bf16* __restrict__ A,
                                                         const bf16* __restrict__ Bt,
                                                         const float* __restrict__ bias,
                                                         OutT* __restrict__ C,
                                                         bf16* __restrict__ vtout,
                                                         int M, int N, int K,
                                                         float qscale, int qcols,
                                                         int nbx) {
  __shared__ alignas(16) char smem[73728];               // 72 KB
  auto As = (bf16(*)[256 * 32])smem;                     // As[3][8192] (48 KB)
  auto Bs = (bf16(*)[128 * 32])(smem + 49152);           // Bs[3][4096] (24 KB)

  const int tid  = threadIdx.x;
  const int lane = tid & 63;
  const int w    = tid >> 6;
  const int wm = w >> 1, wn = w & 1;
  const int l15 = lane & 15, l16 = lane >> 4;

  const int nwg = (int)gridDim.x;
  const int cpx = nwg >> 3;
  const int swz = ((int)blockIdx.x & 7) * cpx + ((int)blockIdx.x >> 3);
  const int m0 = (swz / nbx) * 256;
  const int n0 = (swz % nbx) * 128;

  const int c0  = w * 64 + lane;                 // chunk for A j=0 and B
  const int rA0 = c0 >> 2, sA0 = c0 & 3;
  const int rA1 = rA0 + 128;                     // A j=1 (c0+512)
  const bf16* srcA0 = A  + (size_t)(m0 + rA0) * K + 8 * (sA0 ^ ((rA0 >> 1) & 3));
  const bf16* srcA1 = A  + (size_t)(m0 + rA1) * K + 8 * (sA0 ^ ((rA1 >> 1) & 3));
  const bf16* srcB  = Bt + (size_t)(n0 + rA0) * K + 8 * (sA0 ^ ((rA0 >> 1) & 3));

#define STAGE_TILE(buf, kt)                                       \
  {                                                               \
    const int k0_ = (kt) * 32;                                    \
    async_copy16(&As[buf][(w * 64) * 8],         srcA0 + k0_);    \
    async_copy16(&As[buf][(512 + w * 64) * 8],   srcA1 + k0_);    \
    async_copy16(&Bs[buf][(w * 64) * 8],         srcB  + k0_);    \
  }

  f32x4 acc[4][4];
  f32x4 zf = {0.f, 0.f, 0.f, 0.f};
#pragma unroll
  for (int i = 0; i < 4; ++i)
#pragma unroll
    for (int j = 0; j < 4; ++j) acc[i][j] = zf;

  const int KT = K >> 5;
  STAGE_TILE(0, 0)
  STAGE_TILE(1, 1)

  const int soff = 8 * (l16 ^ ((l15 >> 1) & 3));

  int bufc = 0;
  int bufs = 2;
  for (int kt = 0; kt < KT; ++kt) {
    if (kt < KT - 1) { asm volatile("s_waitcnt vmcnt(3)" ::: "memory"); }
    else             { asm volatile("s_waitcnt vmcnt(0)" ::: "memory"); }
    __builtin_amdgcn_s_barrier();
    asm volatile("" ::: "memory");
    if (kt + 2 < KT) STAGE_TILE(bufs, kt + 2)

    bf16x8 bfr[4], afr[4];
#pragma unroll
    for (int n = 0; n < 4; ++n) {
      int rb = wn * 64 + n * 16 + l15;
      bfr[n] = *(const bf16x8*)(&Bs[bufc][rb * 32 + soff]);
    }
#pragma unroll
    for (int m = 0; m < 4; ++m) {
      int ra = wm * 64 + m * 16 + l15;
      afr[m] = *(const bf16x8*)(&As[bufc][ra * 32 + soff]);
    }
    __builtin_amdgcn_s_setprio(1);
#pragma unroll
    for (int m = 0; m < 4; ++m)
#pragma unroll
      for (int n = 0; n < 4; ++n)
        acc[m][n] = __builtin_amdgcn_mfma_f32_16x16x32_bf16(afr[m], bfr[n], acc[m][n], 0, 0, 0);
    __builtin_amdgcn_s_setprio(0);
    asm volatile("" ::: "memory");
    bufc = (bufc == 2) ? 0 : bufc + 1;
    bufs = (bufs == 2) ? 0 : bufs + 1;
  }

  // ---- epilogue
  if (FUSE_VT && n0 >= 2048) {
    // V-block: coalesced vt writes via LDS overlay T[128 cols][264 rows-pad].
    __syncthreads();                         // all K-loop LDS reads complete
    bf16* T = (bf16*)smem;
#pragma unroll
    for (int n = 0; n < 4; ++n) {
      int c = wn * 64 + n * 16 + l15;
      float bb = bias[n0 + c];
#pragma unroll
      for (int m = 0; m < 4; ++m) {
        int r0_ = wm * 64 + m * 16 + l16 * 4;   // quad base row; key0 % 4 == 0
        int key0 = r0_ & 63;
        int pos0 = (key0 & 32) | (((key0 >> 2) & 3) << 3) | (((key0 >> 4) & 1) << 2);
        int rp = (r0_ & ~63) | pos0;
        bf16x4 q = { (bf16)(acc[m][n][0] + bb), (bf16)(acc[m][n][1] + bb),
                     (bf16)(acc[m][n][2] + bb), (bf16)(acc[m][n][3] + bb) };
        *(bf16x4*)(&T[c * 264 + rp]) = q;
      }
    }
    __syncthreads();
    const int b_  = m0 >> 11;                // batch (tiles never straddle)
    const int s0_ = m0 & 2047;
    const int ck  = tid & 31;                // 16B chunk within a 512B run
#pragma unroll
    for (int pass = 0; pass < 8; ++pass) {
      int c = pass * 16 + (tid >> 5);        // 0..127
      int colg = n0 + c - 2048;
      int hh = colg >> 6, d = colg & 63;
      bf16x8 v = *(const bf16x8*)(&T[c * 264 + ck * 8]);
      *(bf16x8*)(vtout + ((size_t)(b_ * 16 + hh) * 64 + d) * 2048 + s0_ + ck * 8) = v;
    }
    return;
  }
  // Q/K columns: direct C writes
#pragma unroll
  for (int n = 0; n < 4; ++n) {
    int col = n0 + wn * 64 + n * 16 + l15;
    float bb = bias[col];
    float sc2 = (col < qcols) ? qscale : 1.0f;
#pragma unroll
    for (int m = 0; m < 4; ++m) {
#pragma unroll
      for (int reg = 0; reg < 4; ++reg) {
        int row = m0 + wm * 64 + m * 16 + l16 * 4 + reg;
        C[(size_t)row * N + col] = (OutT)((acc[m][n][reg] + bb) * sc2);
      }
    }
  }
#undef STAGE_TILE
}

// ---------------------------------------------------------------------------
// GEMM gemm128 (proj): BM=BN=128, BK=32, 256 thr = 4 waves (2x2), 64x64/wave.
// Triple-buffered LDS (48 KB), counted vmcnt(4), 1 barrier/K-tile.
// Used only for proj (B is L2-resident so small-tile FETCH penalty absorbed).
// ---------------------------------------------------------------------------
template <typename OutT>
__global__ __launch_bounds__(256, 4) void gemm128_kernel(const bf16* __restrict__ A,
                                                         const bf16* __restrict__ Bt,
                                                         const float* __restrict__ bias,
                                                         OutT* __restrict__ C,
                                                         int M, int N, int K,
                                                         int nbx) {
  __shared__ alignas(16) char smem[49152];               // 48 KB
  auto As = (bf16(*)[128 * 32])smem;                     // As[3][4096]
  auto Bs = (bf16(*)[128 * 32])(smem + 24576);           // Bs[3][4096]

  const int tid  = threadIdx.x;
  const int lane = tid & 63;
  const int w    = tid >> 6;          // 0..3
  const int wm = w >> 1, wn = w & 1;
  const int l15 = lane & 15, l16 = lane >> 4;

  const int nwg = (int)gridDim.x;
  const int cpx = nwg >> 3;
  const int swz = ((int)blockIdx.x & 7) * cpx + ((int)blockIdx.x >> 3);
  const int m0 = (swz / nbx) * 128;
  const int n0 = (swz % nbx) * 128;

  const int r0_ = tid >> 2, s0c = tid & 3;
  const int r1_ = r0_ + 64;
  const bf16* srcA0 = A  + (size_t)(m0 + r0_) * K + 8 * (s0c ^ ((r0_ >> 1) & 3));
  const bf16* srcA1 = A  + (size_t)(m0 + r1_) * K + 8 * (s0c ^ ((r1_ >> 1) & 3));
  const bf16* srcB0 = Bt + (size_t)(n0 + r0_) * K + 8 * (s0c ^ ((r0_ >> 1) & 3));
  const bf16* srcB1 = Bt + (size_t)(n0 + r1_) * K + 8 * (s0c ^ ((r1_ >> 1) & 3));

#define STAGE_TILE(buf, kt)                                         \
  {                                                                 \
    const int k0_ = (kt) * 32;                                      \
    async_copy16(&As[buf][(w * 64) * 8],         srcA0 + k0_);      \
    async_copy16(&As[buf][(256 + w * 64) * 8],   srcA1 + k0_);      \
    async_copy16(&Bs[buf][(w * 64) * 8],         srcB0 + k0_);      \
    async_copy16(&Bs[buf][(256 + w * 64) * 8],   srcB1 + k0_);      \
  }

  f32x4 acc[4][4];
  f32x4 zf = {0.f, 0.f, 0.f, 0.f};
#pragma unroll
  for (int i = 0; i < 4; ++i)
#pragma unroll
    for (int j = 0; j < 4; ++j) acc[i][j] = zf;

  const int KT = K >> 5;
  STAGE_TILE(0, 0)
  STAGE_TILE(1, 1)

  const int soff = 8 * (l16 ^ ((l15 >> 1) & 3));

  int bufc = 0;
  int bufs = 2;
  for (int kt = 0; kt < KT; ++kt) {
    if (kt < KT - 1) { asm volatile("s_waitcnt vmcnt(4)" ::: "memory"); }
    else             { asm volatile("s_waitcnt vmcnt(0)" ::: "memory"); }
    __builtin_amdgcn_s_barrier();
    asm volatile("" ::: "memory");
    if (kt + 2 < KT) STAGE_TILE(bufs, kt + 2)

    bf16x8 bfr[4], afr[4];
#pragma unroll
    for (int n = 0; n < 4; ++n) {
      int rb = wn * 64 + n * 16 + l15;
      bfr[n] = *(const bf16x8*)(&Bs[bufc][rb * 32 + soff]);
    }
#pragma unroll
    for (int m = 0; m < 4; ++m) {
      int ra = wm * 64 + m * 16 + l15;
      afr[m] = *(const bf16x8*)(&As[bufc][ra * 32 + soff]);
    }
    __builtin_amdgcn_s_setprio(1);
#pragma unroll
    for (int m = 0; m < 4; ++m)
#pragma unroll
      for (int n = 0; n < 4; ++n)
        acc[m][n] = __builtin_amdgcn_mfma_f32_16x16x32_bf16(afr[m], bfr[n], acc[m][n], 0, 0, 0);
    __builtin_amdgcn_s_setprio(0);
    asm volatile("" ::: "memory");
    bufc = (bufc == 2) ? 0 : bufc + 1;
    bufs = (bufs == 2) ? 0 : bufs + 1;
  }

#pragma unroll
  for (int n = 0; n < 4; ++n) {
    int col = n0 + wn * 64 + n * 16 + l15;
    float bb = bias[col];
#pragma unroll
    for (int m = 0; m < 4; ++m) {
#pragma unroll
      for (int reg = 0; reg < 4; ++reg) {
        int row = m0 + wm * 64 + m * 16 + l16 * 4 + reg;
        C[(size_t)row * N + col] = (OutT)(acc[m][n][reg] + bb);
      }
    }
  }
#undef STAGE_TILE
}

// ---------------------------------------------------------------------------
// Flash attention v6 + XCD-affinity remap. Q-tile 128 rows, 8 waves x 16.
// 1D grid 512: bh = ((i>>6)<<3)|(i&7), bx = (i>>3)&7 -- all 8 blocks sharing
// a bh have the same i%8 residue -> same XCD -> K/V L2 reuse.
// Pair (bx, 15-bx) processed sequentially -> 36 KV-steps/block.
// NO-MAX exp2 softmax (Q pre-scaled by log2e/8; masked entries exp2(-1e30)=0).
// P never touches LDS (vt key axis pre-permuted at QKV-GEMM epilogue;
// in-lane pack: pb[kc] = {sv[2kc][0..3], sv[2kc+1][0..3]}).
// S^T = mfma(K,Q): lane holds col q = lane&15, 16 keys = kf*16 + l16*4 + reg.
// O^T = mfma(V^T,P^T): lane holds col q = lane&15, d = nf*16 + l16*4 + reg.
// LDS = 32 KB (K/V double-buffer only).
// ---------------------------------------------------------------------------
__global__ __launch_bounds__(512, 4) void flash_kernel(const bf16* __restrict__ qkv,
                                                       const bf16* __restrict__ vt,
                                                       bf16* __restrict__ obuf) {
  constexpr int S = 2048, E3 = 3072;
  __shared__ alignas(16) bf16 Ks[2][64 * 64];
  __shared__ alignas(16) bf16 Vs[2][64 * 64];   // V^T tile (key-permuted cols)

  const int tid  = threadIdx.x;
  const int lane = tid & 63;
  const int w    = tid >> 6;
  const int i   = (int)blockIdx.x;            // 0..511
  const int bh  = ((i >> 6) << 3) | (i & 7);  // same-bh blocks share i%8 (XCD)
  const int bx  = (i >> 3) & 7;               // 0..7 -> tiles bx and 15-bx
  const int b = bh >> 4, h = bh & 15;
  const int l15 = lane & 15, l16 = lane >> 4;

  // staging geometry (wave w stages 1KB chunk w of each 64x64 tile)
  const int sr  = w * 8 + (lane >> 3);   // row 0..63 within tile
  const int scc = lane & 7;              // 16B slot
  const bf16* kstage = qkv + (size_t)(b * S + sr) * E3 + 1024 + h * 64 + 8 * (scc ^ (sr & 7));
  const bf16* vstage = vt + (size_t)(bh * 64 + sr) * S + 8 * (scc ^ (sr & 7));

  // hoisted LDS byte offsets (row stride 128B; XOR term reduces to l15&7)
  const int xsw = l15 & 7;
  const uint32_t rdA = (uint32_t)(l15 * 128 + 16 * (l16 ^ xsw));        // chunk 0
  const uint32_t rdB = (uint32_t)(l15 * 128 + 16 * ((4 + l16) ^ xsw));  // chunk 1

#define KV_STAGE(buf, kv0_)                                        \
  {                                                                \
    async_copy16(Ks[buf] + w * 512, kstage + (size_t)(kv0_) * E3); \
    async_copy16(Vs[buf] + w * 512, vstage + (kv0_));              \
  }

  for (int half = 0; half < 2; ++half) {
    const int t = half ? (15 - bx) : bx;
    const int q0 = t * 128;
    const int wq0 = q0 + w * 16;         // first q row owned by this wave
    const int nsteps = 2 * t + 2;        // even

    KV_STAGE(0, 0)

    // Q fragments global->reg (B-operand: col q = l15, k-chunk dk*32+l16*8)
    bf16x8 qf[2];
    {
      const bf16* qbase = qkv + (size_t)(b * S + wq0 + l15) * E3 + h * 64;
#pragma unroll
      for (int dk = 0; dk < 2; ++dk)
        qf[dk] = *(const bf16x8*)(qbase + (dk * 4 + l16) * 8);
    }

    float lstate = 0.f;
    f32x4 oacc[4];
    f32x4 zf = {0.f, 0.f, 0.f, 0.f};
#pragma unroll
    for (int i2 = 0; i2 < 4; ++i2) oacc[i2] = zf;

    __syncthreads();   // step-0 K/V staged (vmcnt drained by barrier)

#define FLASH_STEP(CUR, STEPIDX)                                                  \
    {                                                                             \
      const int kv0 = (STEPIDX) * 64;                                             \
      if ((STEPIDX) + 1 < nsteps) KV_STAGE((CUR) ^ 1, kv0 + 64)                   \
      if (kv0 <= wq0 + 15) {   /* wave-uniform dead-step skip */                  \
        f32x4 sv[4];                                                              \
        _Pragma("unroll")                                                         \
        for (int kf = 0; kf < 4; ++kf) sv[kf] = zf;                               \
        __builtin_amdgcn_s_setprio(1);                                            \
        _Pragma("unroll")                                                         \
        for (int kf = 0; kf < 4; ++kf) {                                          \
          bf16x8 k0 = *(const bf16x8*)((const char*)Ks[CUR] + rdA + kf * 2048);   \
          sv[kf] = __builtin_amdgcn_mfma_f32_16x16x32_bf16(k0, qf[0], sv[kf], 0, 0, 0); \
          bf16x8 k1 = *(const bf16x8*)((const char*)Ks[CUR] + rdB + kf * 2048);   \
          sv[kf] = __builtin_amdgcn_mfma_f32_16x16x32_bf16(k1, qf[1], sv[kf], 0, 0, 0); \
        }                                                                         \
        __builtin_amdgcn_s_setprio(0);                                            \
        if (kv0 + 63 > wq0) {   /* causal mask (diagonal-crossing steps only) */  \
          const int qrow_ = wq0 + l15;                                            \
          _Pragma("unroll")                                                       \
          for (int kf = 0; kf < 4; ++kf)                                          \
            _Pragma("unroll")                                                     \
            for (int reg = 0; reg < 4; ++reg) {                                   \
              int key = kv0 + kf * 16 + l16 * 4 + reg;                            \
              if (key > qrow_) sv[kf][reg] = -1e30f;                              \
            }                                                                     \
        }                                                                         \
        float rsum = 0.f;                                                         \
        _Pragma("unroll")                                                         \
        for (int kf = 0; kf < 4; ++kf)                                            \
          _Pragma("unroll")                                                       \
          for (int reg = 0; reg < 4; ++reg) {                                     \
            float p = __builtin_amdgcn_exp2f(sv[kf][reg]);                        \
            sv[kf][reg] = p;                                                      \
            rsum += p;                                                            \
          }                                                                       \
        rsum += __shfl_xor(rsum, 16);                                             \
        rsum += __shfl_xor(rsum, 32);                                             \
        lstate += rsum;                                                           \
        /* in-lane P pack: pb[kc] covers permuted key positions kc*32+8g+j */     \
        bf16x8 pb[2];                                                             \
        _Pragma("unroll")                                                         \
        for (int kc = 0; kc < 2; ++kc) {                                          \
          bf16x8 tq;                                                              \
          tq[0] = (bf16)sv[2 * kc][0];  tq[1] = (bf16)sv[2 * kc][1];              \
          tq[2] = (bf16)sv[2 * kc][2];  tq[3] = (bf16)sv[2 * kc][3];              \
          tq[4] = (bf16)sv[2 * kc + 1][0]; tq[5] = (bf16)sv[2 * kc + 1][1];       \
          tq[6] = (bf16)sv[2 * kc + 1][2]; tq[7] = (bf16)sv[2 * kc + 1][3];       \
          pb[kc] = tq;                                                            \
        }                                                                         \
        __builtin_amdgcn_s_setprio(1);                                            \
        _Pragma("unroll")                                                         \
        for (int nf = 0; nf < 4; ++nf) {                                          \
          bf16x8 vf0 = *(const bf16x8*)((const char*)Vs[CUR] + rdA + nf * 2048);  \
          oacc[nf] = __builtin_amdgcn_mfma_f32_16x16x32_bf16(vf0, pb[0], oacc[nf], 0, 0, 0); \
          bf16x8 vf1 = *(const bf16x8*)((const char*)Vs[CUR] + rdB + nf * 2048);  \
          oacc[nf] = __builtin_amdgcn_mfma_f32_16x16x32_bf16(vf1, pb[1], oacc[nf], 0, 0, 0); \
        }                                                                         \
        __builtin_amdgcn_s_setprio(0);                                            \
      }                                                                           \
      __syncthreads();   /* next buffer staged + all waves done with CUR */       \
    }

    for (int step = 0; step < nsteps; step += 2) {
      FLASH_STEP(0, step)
      FLASH_STEP(1, step + 1)
    }
#undef FLASH_STEP

    // ---- normalize and store: lane owns q row; d = nf*16 + l16*4 + reg
    float inv = 1.0f / lstate;
    int qrow = wq0 + l15;
#pragma unroll
    for (int nf = 0; nf < 4; ++nf) {
      bf16x4 o4 = { (bf16)(oacc[nf][0] * inv), (bf16)(oacc[nf][1] * inv),
                    (bf16)(oacc[nf][2] * inv), (bf16)(oacc[nf][3] * inv) };
      *(bf16x4*)(obuf + (size_t)(b * S + qrow) * 1024 + h * 64 + nf * 16 + l16 * 4) = o4;
    }
  }
#undef KV_STAGE
}

// ---------------------------------------------------------------------------
extern "C" void kernel_launch(void* const* d_in, const int* in_sizes, int n_in,
                              void* d_out, int out_size, void* d_ws, size_t ws_size,
                              hipStream_t stream) {
  (void)in_sizes; (void)n_in; (void)out_size; (void)ws_size;
  const float* x      = (const float*)d_in[0];
  const float* w_attn = (const float*)d_in[1];
  const float* b_attn = (const float*)d_in[2];
  const float* w_proj = (const float*)d_in[3];
  const float* b_proj = (const float*)d_in[4];
  float* out = (float*)d_out;

  char* ws = (char*)d_ws;
  bf16* xb  = (bf16*)(ws + 0);          // 8192*1024*2  = 16777216
  bf16* wat = (bf16*)(ws + 16777216);   // 3072*1024*2  =  6291456
  bf16* wpt = (bf16*)(ws + 23068672);   // 1024*1024*2  =  2097152
  bf16* qkv = (bf16*)(ws + 25165824);   // 8192*3072*2  = 50331648
  bf16* vt  = (bf16*)(ws + 75497472);   // 64*64*2048*2 = 16777216
  bf16* ob  = (bf16*)(ws + 92274688);   // 8192*1024*2  = 16777216 (end 109051904)

  const float QSCALE = 0.18033688011112042f;   // log2(e) / sqrt(64)

  cast_x_kernel<<<2048, 256, 0, stream>>>(x, xb, 8192 * 1024 / 4);
  transpose_cast_kernel<<<dim3(48, 16), 256, 0, stream>>>(w_attn, wat, 1024, 3072);
  transpose_cast_kernel<<<dim3(16, 16), 256, 0, stream>>>(w_proj, wpt, 1024, 1024);
  // QKV (+fused V-transpose): grid (8192/256)*(3072/128) = 768 blocks (%8==0)
  gemm256_kernel<bf16, true><<<768, 512, 0, stream>>>(xb, wat, b_attn, qkv, vt,
                                                      8192, 3072, 1024, QSCALE, 1024, 24);
  flash_kernel<<<512, 512, 0, stream>>>(qkv, vt, ob);
  // proj: grid (8192/128)*(1024/128) = 512 blocks (%8==0), 2x co-residency
  gemm128_kernel<float><<<512, 256, 0, stream>>>(ob, wpt, b_proj, out,
                                                 8192, 1024, 1024, 8);
}